// Round 13
// baseline (25.145 us; speedup 1.0000x reference)
//
#include <hip/hip_runtime.h>
#include <hip/hip_fp16.h>

#define DIM 192
#define RROWS 25  // provable: staged span <= 15 + 2*(192/ds) + 1 <= 24 for ds>=48 (sr in [1,4))

// nearest-resample index map for pass 1 (mid index t -> vol index),
// bit-exact with: clip(round(clip(t / dz, 0, 192)), 0, 191)
__device__ __forceinline__ int nearest_map(int t, float dz) {
    float dl = (float)t / dz;                 // same float div as jnp
    dl = fminf(fmaxf(dl, 0.0f), 192.0f);      // layer clip to [0, inshape]
    float r = rintf(dl);                      // round half-to-even == jnp.round
    r = fminf(r, 191.0f);                     // interp_nearest clip
    return (int)r;
}

// packed per-axis LUT entry: half_bits(w0) | n0<<16 | n1<<24  (n <= 191 < 256)
// identical float-op order to the reference pipeline.
__device__ __forceinline__ unsigned int make_entry(int i, float sr) {
    const float dsf = (float)(int)(192.0f / sr);   // ds = int32(192/sr)
    const float uz  = 192.0f / dsf;
    const float dz  = dsf / 192.0f;
    float l = (float)i / uz;
    l = fminf(fmaxf(l, 0.0f), 191.0f);
    const float f0 = floorf(l);
    const float f1 = fminf(f0 + 1.0f, 191.0f);
    const float w0 = f1 - l;
    const int n0 = nearest_map((int)f0, dz);
    const int n1 = nearest_map((int)f1, dz);
    const __half hw = __float2half(w0);
    return (unsigned int)__half_as_ushort(hw) | ((unsigned int)n0 << 16) | ((unsigned int)n1 << 24);
}

__device__ __forceinline__ unsigned int pack_h2(float a, float b) {
    __half2 h = __floats2half2_rn(a, b);
    return *reinterpret_cast<unsigned int*>(&h);
}

__device__ __forceinline__ _Float16 u16_as_h(unsigned short u) {
    union { unsigned short u; _Float16 h; } cv;
    cv.u = u;
    return cv.h;
}

// ---- single fused kernel, x-lerp folded into staging ----
// Block: one (b,x), ONE 16-row y-tile, 256 threads (4 waves).
// Staged LDS value = fp16( vol[x0]*w0x + vol[x1]*w1x )  (scalar u16).
// Compute: 4 ds_read_u16 + scalar f16 z/y lerp per output.
__global__ __launch_bounds__(256, 8) void mimic_acq_xl_kernel(
    const float* __restrict__ vol,    // [2,192,192,192,1]
    const float* __restrict__ sres,   // [2,3]
    float* __restrict__ out)          // [2,192,192,192,1]
{
    __shared__ unsigned short lds16[RROWS * DIM];   // 9600 B
    __shared__ unsigned int zside[DIM];             // 768 B
    __shared__ unsigned int yside[16];              // 64 B
    __shared__ float xw_s;                          // 4 B
    __shared__ unsigned int xn_s;                   // 4 B

    const int tz  = threadIdx.x;            // 0..63  (z lane)
    const int ty  = threadIdx.y;            // 0..3   (wave index)
    const int tid = ty * 64 + tz;

    const int bid = blockIdx.x;             // 0..4607
    const int wg  = (bid & 7) * 576 + (bid >> 3);   // XCD-chunked (4608 = 8*576)
    const int bx  = wg / 12;                // b*192 + x
    const int tile = wg % 12;               // ytile
    const int b   = (bx >= DIM) ? 1 : 0;
    const int x   = bx - b * DIM;
    const int y0t = tile * 16;

    // ---- distributed LUT-entry build: one chain per thread ----
    if (tid < DIM) {
        zside[tid] = make_entry(tid, sres[b * 3 + 2]);
    } else if (tid < DIM + 16) {
        yside[tid - DIM] = make_entry(y0t + (tid - DIM), sres[b * 3 + 1]);
    } else if (tid == DIM + 16) {
        // x entry with f32 weight (x-lerp applied at stage time in f32)
        const float srx = sres[b * 3 + 0];
        const float dsf = (float)(int)(192.0f / srx);
        const float uz  = 192.0f / dsf;
        const float dz  = dsf / 192.0f;
        float l = (float)x / uz;
        l = fminf(fmaxf(l, 0.0f), 191.0f);
        const float f0 = floorf(l);
        const float f1 = fminf(f0 + 1.0f, 191.0f);
        xw_s = f1 - l;
        xn_s = (unsigned int)nearest_map((int)f0, dz)
             | ((unsigned int)nearest_map((int)f1, dz) << 8);
    }
    __syncthreads();

    // block-uniform x / y-range from LDS
    const float w0x = xw_s, w1x = 1.0f - xw_s;
    const unsigned int xpk = xn_s;
    const int nx0 = (int)(xpk & 0xffu);
    const int nx1 = (int)(xpk >> 8);
    const int nymin = (int)((yside[0] >> 16) & 0xffu);
    const int R = (int)(yside[15] >> 24) - nymin + 1;   // <= 25

    // ---- stage: load f32 pairs, x-lerp in f32, store fp16 scalar ----
    {
        const float* vb = vol + (size_t)b * (DIM * DIM * DIM);
        const float* r0 = vb + ((size_t)nx0 * DIM + nymin) * DIM;
        const float* r1 = vb + ((size_t)nx1 * DIM + nymin) * DIM;
        const int C = R * 48;
        for (int c = tid; c < C; c += 256) {
            const int yy = c / 48;
            const int z4 = (c - yy * 48) * 4;
            const float4 v0 = *(const float4*)(r0 + yy * DIM + z4);
            const float4 v1 = *(const float4*)(r1 + yy * DIM + z4);
            const float m0 = v0.x * w0x + v1.x * w1x;
            const float m1 = v0.y * w0x + v1.y * w1x;
            const float m2 = v0.z * w0x + v1.z * w1x;
            const float m3 = v0.w * w0x + v1.w * w1x;
            uint2 q;
            q.x = pack_h2(m0, m1);
            q.y = pack_h2(m2, m3);
            *(uint2*)&lds16[yy * DIM + z4] = q;
        }
    }

    // z entries for this lane's 3 z positions (LDS reads overlap staging)
    _Float16 wz0h[3], wz1h[3];
    int zz0[3], zz1[3];
#pragma unroll
    for (int k = 0; k < 3; ++k) {
        const unsigned int u = zside[tz + k * 64];
        wz0h[k] = u16_as_h((unsigned short)(u & 0xffffu));
        wz1h[k] = (_Float16)1.0f - wz0h[k];
        zz0[k]  = (int)((u >> 16) & 0xffu);
        zz1[k]  = (int)(u >> 24);
    }

    __syncthreads();

    // ---- compute: 4 y rows x 3 z per thread, scalar f16 z/y lerp ----
#pragma unroll
    for (int yj = 0; yj < 4; ++yj) {
        const int ly = ty * 4 + yj;
        const int y  = y0t + ly;
        const unsigned int uy = yside[ly];
        const _Float16 w0yh = u16_as_h((unsigned short)(uy & 0xffffu));
        const _Float16 w1yh = (_Float16)1.0f - w0yh;
        const int rr0 = ((int)((uy >> 16) & 0xffu) - nymin) * DIM;
        const int rr1 = ((int)(uy >> 24) - nymin) * DIM;
        float* ob = out + ((size_t)bx * DIM + y) * DIM + tz;
#pragma unroll
        for (int k = 0; k < 3; ++k) {
            const _Float16 s00 = u16_as_h(lds16[rr0 + zz0[k]]);
            const _Float16 s10 = u16_as_h(lds16[rr0 + zz1[k]]);
            const _Float16 s01 = u16_as_h(lds16[rr1 + zz0[k]]);
            const _Float16 s11 = u16_as_h(lds16[rr1 + zz1[k]]);

            const _Float16 l0 = s00 * wz0h[k] + s10 * wz1h[k];   // z-lerp at y0
            const _Float16 l1 = s01 * wz0h[k] + s11 * wz1h[k];   // z-lerp at y1
            const _Float16 m  = l0 * w0yh + l1 * w1yh;           // y-lerp

            __builtin_nontemporal_store((float)m, ob + k * 64);
        }
    }
}

extern "C" void kernel_launch(void* const* d_in, const int* in_sizes, int n_in,
                              void* d_out, int out_size, void* d_ws, size_t ws_size,
                              hipStream_t stream) {
    const float* vol  = (const float*)d_in[0];
    const float* sres = (const float*)d_in[1];
    float* out = (float*)d_out;

    dim3 block(64, 4, 1);
    dim3 grid(4608, 1, 1);   // (b*192+x) * 12 ytiles, XCD-swizzled in-kernel
    hipLaunchKernelGGL(mimic_acq_xl_kernel, grid, block, 0, stream, vol, sres, out);
}

// Round 14
// 24.763 us; speedup vs baseline: 1.0154x; 1.0154x over previous
//
#include <hip/hip_runtime.h>
#include <hip/hip_fp16.h>

#define DIM 192
#define RROWS 25  // provable: staged span <= 15 + 2*(192/ds) + 1 <= 24 for ds>=48 (sr in [1,4))

typedef _Float16 h2v __attribute__((ext_vector_type(2)));

// nearest-resample index map for pass 1 (mid index t -> vol index),
// bit-exact with: clip(round(clip(t / dz, 0, 192)), 0, 191)
__device__ __forceinline__ int nearest_map(int t, float dz) {
    float dl = (float)t / dz;                 // same float div as jnp
    dl = fminf(fmaxf(dl, 0.0f), 192.0f);      // layer clip to [0, inshape]
    float r = rintf(dl);                      // round half-to-even == jnp.round
    r = fminf(r, 191.0f);                     // interp_nearest clip
    return (int)r;
}

// packed per-axis LUT entry: half_bits(w0) | n0<<16 | n1<<24  (n <= 191 < 256)
// identical float-op order to the reference pipeline.
__device__ __forceinline__ unsigned int make_entry(int i, float sr) {
    const float dsf = (float)(int)(192.0f / sr);   // ds = int32(192/sr)
    const float uz  = 192.0f / dsf;
    const float dz  = dsf / 192.0f;
    float l = (float)i / uz;
    l = fminf(fmaxf(l, 0.0f), 191.0f);
    const float f0 = floorf(l);
    const float f1 = fminf(f0 + 1.0f, 191.0f);
    const float w0 = f1 - l;
    const int n0 = nearest_map((int)f0, dz);
    const int n1 = nearest_map((int)f1, dz);
    const __half hw = __float2half(w0);
    return (unsigned int)__half_as_ushort(hw) | ((unsigned int)n0 << 16) | ((unsigned int)n1 << 24);
}

__device__ __forceinline__ unsigned int pack_h2(float a, float b) {
    __half2 h = __floats2half2_rn(a, b);
    return *reinterpret_cast<unsigned int*>(&h);
}

__device__ __forceinline__ h2v as_h2v(unsigned int u) {
    union { unsigned int u; h2v h; } cv;
    cv.u = u;
    return cv.h;
}

// broadcast the low half of u into both lanes of an h2v
__device__ __forceinline__ h2v bcast_h(unsigned int u) {
    union { unsigned int u; h2v h; } cv;
    cv.u = (u & 0xffffu) * 0x10001u;
    return cv.h;
}

// ---- single fused kernel ----
// Block: one (b,x), ONE 16-row y-tile, 256 threads (4 waves).
// Distributed LUT build: 1 entry chain per thread (192 z + 16 y + 1 x = 209),
// shared via LDS. fp16-pair main tile + fp16 packed lerp. ~20 KB LDS ->
// 8 blocks/CU = 32 waves/CU. XCD-chunked block swizzle.
__global__ __launch_bounds__(256, 8) void mimic_acq_f1_kernel(
    const float* __restrict__ vol,    // [2,192,192,192,1]
    const float* __restrict__ sres,   // [2,3]
    float* __restrict__ out)          // [2,192,192,192,1]
{
    __shared__ unsigned int lds[RROWS * DIM];   // 19200 B
    __shared__ unsigned int zside[DIM];         // 768 B
    __shared__ unsigned int yside[16];          // 64 B
    __shared__ float xw_s;                      // 4 B
    __shared__ unsigned int xn_s;               // 4 B

    const int tz  = threadIdx.x;            // 0..63  (z lane)
    const int ty  = threadIdx.y;            // 0..3
    const int tid = ty * 64 + tz;

    const int bid = blockIdx.x;             // 0..4607
    const int wg  = (bid & 7) * 576 + (bid >> 3);   // XCD-chunked (4608 = 8*576)
    const int bx  = wg / 12;                // b*192 + x
    const int tile = wg % 12;               // ytile
    const int b   = (bx >= DIM) ? 1 : 0;
    const int x   = bx - b * DIM;
    const int y0t = tile * 16;

    // ---- distributed LUT-entry build: one chain per thread ----
    if (tid < DIM) {
        zside[tid] = make_entry(tid, sres[b * 3 + 2]);
    } else if (tid < DIM + 16) {
        yside[tid - DIM] = make_entry(y0t + (tid - DIM), sres[b * 3 + 1]);
    } else if (tid == DIM + 16) {
        // x entry with f32 weight (final lerp stays f32)
        const float srx = sres[b * 3 + 0];
        const float dsf = (float)(int)(192.0f / srx);
        const float uz  = 192.0f / dsf;
        const float dz  = dsf / 192.0f;
        float l = (float)x / uz;
        l = fminf(fmaxf(l, 0.0f), 191.0f);
        const float f0 = floorf(l);
        const float f1 = fminf(f0 + 1.0f, 191.0f);
        xw_s = f1 - l;
        xn_s = (unsigned int)nearest_map((int)f0, dz)
             | ((unsigned int)nearest_map((int)f1, dz) << 8);
    }
    __syncthreads();

    // block-uniform x / y-range from LDS
    const float w0x = xw_s, w1x = 1.0f - xw_s;
    const unsigned int xpk = xn_s;
    const int nx0 = (int)(xpk & 0xffu);
    const int nx1 = (int)(xpk >> 8);
    const int nymin = (int)((yside[0] >> 16) & 0xffu);
    const int R = (int)(yside[15] >> 24) - nymin + 1;   // <= 25

    // ---- stage (load f32 pairs, pack to half2) ----
    {
        const float* vb = vol + (size_t)b * (DIM * DIM * DIM);
        const float* r0 = vb + ((size_t)nx0 * DIM + nymin) * DIM;
        const float* r1 = vb + ((size_t)nx1 * DIM + nymin) * DIM;
        const int C = R * 48;
        for (int c = tid; c < C; c += 256) {
            const int yy = c / 48;
            const int z4 = (c - yy * 48) * 4;
            const float4 v0 = *(const float4*)(r0 + yy * DIM + z4);
            const float4 v1 = *(const float4*)(r1 + yy * DIM + z4);
            uint4 q;
            q.x = pack_h2(v0.x, v1.x);
            q.y = pack_h2(v0.y, v1.y);
            q.z = pack_h2(v0.z, v1.z);
            q.w = pack_h2(v0.w, v1.w);
            *(uint4*)&lds[yy * DIM + z4] = q;
        }
    }

    // z entries for this lane's 3 z positions (LDS reads overlap staging)
    h2v wz0h[3], wz1h[3];
    int zz0[3], zz1[3];
    const h2v ones = { (_Float16)1.0f, (_Float16)1.0f };
#pragma unroll
    for (int k = 0; k < 3; ++k) {
        const unsigned int u = zside[tz + k * 64];
        wz0h[k] = bcast_h(u);
        wz1h[k] = ones - wz0h[k];
        zz0[k]  = (int)((u >> 16) & 0xffu);
        zz1[k]  = (int)(u >> 24);
    }

    __syncthreads();

    // ---- compute: 4 y rows x 3 z per thread, fp16 packed lerp ----
#pragma unroll
    for (int yj = 0; yj < 4; ++yj) {
        const int ly = ty * 4 + yj;
        const int y  = y0t + ly;
        const unsigned int uy = yside[ly];
        const h2v w0yh = bcast_h(uy);
        const h2v w1yh = ones - w0yh;
        const int rr0 = ((int)((uy >> 16) & 0xffu) - nymin) * DIM;
        const int rr1 = ((int)(uy >> 24) - nymin) * DIM;
        float* ob = out + ((size_t)bx * DIM + y) * DIM + tz;
#pragma unroll
        for (int k = 0; k < 3; ++k) {
            const h2v p00 = as_h2v(lds[rr0 + zz0[k]]);   // {v000, v100}
            const h2v p01 = as_h2v(lds[rr1 + zz0[k]]);   // {v010, v110}
            const h2v p10 = as_h2v(lds[rr0 + zz1[k]]);   // {v001, v101}
            const h2v p11 = as_h2v(lds[rr1 + zz1[k]]);   // {v011, v111}

            const h2v l0 = p00 * wz0h[k] + p10 * wz1h[k];   // z-lerp at y0 (pk f16)
            const h2v l1 = p01 * wz0h[k] + p11 * wz1h[k];   // z-lerp at y1
            const h2v m  = l0 * w0yh + l1 * w1yh;           // y-lerp (pk f16)

            const float r = (float)m.x * w0x + (float)m.y * w1x;  // x-lerp f32
            __builtin_nontemporal_store(r, ob + k * 64);
        }
    }
}

extern "C" void kernel_launch(void* const* d_in, const int* in_sizes, int n_in,
                              void* d_out, int out_size, void* d_ws, size_t ws_size,
                              hipStream_t stream) {
    const float* vol  = (const float*)d_in[0];
    const float* sres = (const float*)d_in[1];
    float* out = (float*)d_out;

    dim3 block(64, 4, 1);
    dim3 grid(4608, 1, 1);   // (b*192+x) * 12 ytiles, XCD-swizzled in-kernel
    hipLaunchKernelGGL(mimic_acq_f1_kernel, grid, block, 0, stream, vol, sres, out);
}